// Round 3
// baseline (511.029 us; speedup 1.0000x reference)
//
#include <hip/hip_runtime.h>
#include <hip/hip_bf16.h>
#include <math.h>

#define NN 8192
#define FIN 256
#define FOUT 64
#define LRELU_ALPHA 0.2f
#define TI 16
#define TJ 256

// ---------------------------------------------------------------------------
// Kernel A: Wh = h @ W  [N,64];  Wh1 = Wh @ a[:64];  Wh2 = Wh @ a[64:]
// block = 256 threads = 4 waves; each wave computes 4 rows (lane = column)
// grid = N/16 = 512 blocks
// ---------------------------------------------------------------------------
__global__ __launch_bounds__(256) void gat_wh_kernel(
    const float* __restrict__ h, const float* __restrict__ W,
    const float* __restrict__ a, float* __restrict__ Wh,
    float* __restrict__ Wh1, float* __restrict__ Wh2) {
  const int t = threadIdx.x;
  const int w = t >> 6;
  const int c = t & 63;
  const int row0 = blockIdx.x * 16 + w * 4;

  float acc0 = 0.f, acc1 = 0.f, acc2 = 0.f, acc3 = 0.f;
  for (int k = 0; k < FIN; ++k) {
    float wv = W[k * FOUT + c];               // wave-coalesced 256B, L1/L2 hot
    acc0 = fmaf(h[(row0 + 0) * FIN + k], wv, acc0);  // wave-uniform -> s_load
    acc1 = fmaf(h[(row0 + 1) * FIN + k], wv, acc1);
    acc2 = fmaf(h[(row0 + 2) * FIN + k], wv, acc2);
    acc3 = fmaf(h[(row0 + 3) * FIN + k], wv, acc3);
  }

  const float a1 = a[c];
  const float a2 = a[FOUT + c];
  float accs[4] = {acc0, acc1, acc2, acc3};
#pragma unroll
  for (int rr = 0; rr < 4; ++rr) {
    Wh[(row0 + rr) * FOUT + c] = accs[rr];
    float v1 = accs[rr] * a1;
    float v2 = accs[rr] * a2;
#pragma unroll
    for (int off = 32; off; off >>= 1) {
      v1 += __shfl_xor(v1, off);
      v2 += __shfl_xor(v2, off);
    }
    if (c == 0) {
      Wh1[row0 + rr] = v1;
      Wh2[row0 + rr] = v2;
    }
  }
}

// ---------------------------------------------------------------------------
// Kernel B: fused mask -> exp -> softmax-denom -> PV -> ELU
// One block per TI=16 output rows. 256 threads = 4 waves.
// Per j-tile (TJ=256):
//   phase 1: all threads compute p = adj>0 ? exp(lrelu(Wh1_i+Wh2_j)) : 0
//            thread t handles x=t for all 16 rows; p -> LDS [16][260]
//            (bank = (4r+t)%32: 2-way aliasing only = free)
//   phase 2: wave w handles x in [64w,64w+64); lane c owns output column c;
//            acc[16] registers; p read as broadcast float4; Wh coalesced.
// No running max: scores bounded (~19), exp fits f32 comfortably.
// ---------------------------------------------------------------------------
__global__ __launch_bounds__(256) void gat_attn_kernel(
    const int* __restrict__ adj, const float* __restrict__ Wh,
    const float* __restrict__ Wh1, const float* __restrict__ Wh2,
    float* __restrict__ out) {
  __shared__ __align__(16) float p_lds[TI][TJ + 4];   // 16x260 floats
  __shared__ float red[4][TI][FOUT];                  // 16 KB cross-wave reduce
  __shared__ float denom_lds[TI];

  const int t = threadIdx.x;
  const int w = t >> 6;
  const int c = t & 63;
  const int i0 = blockIdx.x * TI;

  if (t < TI) denom_lds[t] = 0.f;

  float w1r[TI];
#pragma unroll
  for (int r = 0; r < TI; ++r) w1r[r] = Wh1[i0 + r];

  float dsum[TI];
  float acc[TI];
#pragma unroll
  for (int r = 0; r < TI; ++r) { dsum[r] = 0.f; acc[r] = 0.f; }

  __syncthreads();  // denom_lds init visible before end-of-kernel atomics

  for (int jb = 0; jb < NN; jb += TJ) {
    // ---- phase 1: scores -> p in LDS ----
    const float w2r = Wh2[jb + t];
#pragma unroll
    for (int r = 0; r < TI; ++r) {
      const int av = adj[(i0 + r) * NN + jb + t];  // coalesced 1KB per row
      float v = w1r[r] + w2r;
      v = v > 0.f ? v : LRELU_ALPHA * v;
      float p = (av > 0) ? __expf(v) : 0.f;
      p_lds[r][t] = p;
      dsum[r] += p;
    }
    __syncthreads();

    // ---- phase 2: PV accumulate ----
    const int xb = w * 64;
#pragma unroll 2
    for (int xx = 0; xx < 64; xx += 4) {
      const int x = xb + xx;
      const float* whp = &Wh[(jb + x) * FOUT + c];
      const float wh0 = whp[0];
      const float wh1 = whp[FOUT];
      const float wh2 = whp[2 * FOUT];
      const float wh3 = whp[3 * FOUT];
#pragma unroll
      for (int r = 0; r < TI; ++r) {
        const float4 pv = *(const float4*)&p_lds[r][x];  // LDS broadcast
        float av = acc[r];
        av = fmaf(pv.x, wh0, av);
        av = fmaf(pv.y, wh1, av);
        av = fmaf(pv.z, wh2, av);
        av = fmaf(pv.w, wh3, av);
        acc[r] = av;
      }
    }
    __syncthreads();  // p_lds reused next tile
  }

  // ---- denom reduction: wave-reduce then LDS atomic ----
#pragma unroll
  for (int r = 0; r < TI; ++r) {
    float v = dsum[r];
#pragma unroll
    for (int off = 32; off; off >>= 1) v += __shfl_xor(v, off);
    if (c == 0) atomicAdd(&denom_lds[r], v);
  }

  // ---- cross-wave acc reduction ----
#pragma unroll
  for (int r = 0; r < TI; ++r) red[w][r][c] = acc[r];
  __syncthreads();

  for (int idx = t; idx < TI * FOUT; idx += 256) {
    const int r = idx >> 6;
    const int cc = idx & 63;
    float s = red[0][r][cc] + red[1][r][cc] + red[2][r][cc] + red[3][r][cc];
    float val = s / denom_lds[r];
    val = val > 0.f ? val : expm1f(val);  // ELU (alpha=1)
    out[(i0 + r) * FOUT + cc] = val;
  }
}

extern "C" void kernel_launch(void* const* d_in, const int* in_sizes, int n_in,
                              void* d_out, int out_size, void* d_ws,
                              size_t ws_size, hipStream_t stream) {
  const float* h = (const float*)d_in[0];
  const int* adj = (const int*)d_in[1];
  const float* W = (const float*)d_in[2];
  const float* a = (const float*)d_in[3];
  float* out = (float*)d_out;

  float* Wh = (float*)d_ws;            // N*FOUT floats = 2 MB
  float* Wh1 = Wh + NN * FOUT;         // N floats
  float* Wh2 = Wh1 + NN;               // N floats

  gat_wh_kernel<<<NN / 16, 256, 0, stream>>>(h, W, a, Wh, Wh1, Wh2);
  gat_attn_kernel<<<NN / TI, 256, 0, stream>>>(adj, Wh, Wh1, Wh2, out);
}

// Round 4
// 116.929 us; speedup vs baseline: 4.3704x; 4.3704x over previous
//
#include <hip/hip_runtime.h>
#include <hip/hip_bf16.h>
#include <math.h>

#define NN 8192
#define FIN 256
#define FOUT 64
#define LRELU_ALPHA 0.2f
#define TI 16          // rows per block (MFMA M)
#define TJ 256         // j-tile width
#define JS 4           // j-range split factor (occupancy)
#define JCHUNK (NN / JS)

typedef __attribute__((ext_vector_type(8))) short short8v;
typedef __attribute__((ext_vector_type(4))) float f32x4;

static __device__ inline unsigned short f2bf(float f) {
  union { float f; unsigned u; } v; v.f = f;
  unsigned r = v.u + 0x7fff + ((v.u >> 16) & 1);  // RNE
  return (unsigned short)(r >> 16);
}

// ---------------------------------------------------------------------------
// Kernel A: acc = h @ W (f32); emits WhT bf16 [64][8192] (transposed, feeds
// MFMA B-frags), Wh1 = Wh@a1, Wh2 = Wh@a2 (f32).
// grid 512 x 256 thr; wave w owns rows blk*16 + w*4 .. +3, lane c = column.
// ---------------------------------------------------------------------------
__global__ __launch_bounds__(256) void gat_wh2(
    const float* __restrict__ h, const float* __restrict__ W,
    const float* __restrict__ a, unsigned short* __restrict__ WhT,
    float* __restrict__ Wh1, float* __restrict__ Wh2) {
  __shared__ unsigned short ldsT[64][20];  // [col][row-in-block], padded

  const int t = threadIdx.x;
  const int w = t >> 6;
  const int c = t & 63;
  const int rowblk = blockIdx.x * TI;
  const int row0 = rowblk + w * 4;

  float acc0 = 0.f, acc1 = 0.f, acc2 = 0.f, acc3 = 0.f;
  for (int k = 0; k < FIN; ++k) {
    float wv = W[k * FOUT + c];
    acc0 = fmaf(h[(row0 + 0) * FIN + k], wv, acc0);
    acc1 = fmaf(h[(row0 + 1) * FIN + k], wv, acc1);
    acc2 = fmaf(h[(row0 + 2) * FIN + k], wv, acc2);
    acc3 = fmaf(h[(row0 + 3) * FIN + k], wv, acc3);
  }

  const float a1 = a[c];
  const float a2 = a[FOUT + c];
  float accs[4] = {acc0, acc1, acc2, acc3};
#pragma unroll
  for (int rr = 0; rr < 4; ++rr) {
    ldsT[c][w * 4 + rr] = f2bf(accs[rr]);
    float v1 = accs[rr] * a1;
    float v2 = accs[rr] * a2;
#pragma unroll
    for (int off = 32; off; off >>= 1) {
      v1 += __shfl_xor(v1, off);
      v2 += __shfl_xor(v2, off);
    }
    if (c == 0) {
      Wh1[row0 + rr] = v1;
      Wh2[row0 + rr] = v2;
    }
  }
  __syncthreads();

  // write WhT[col][rowblk .. rowblk+15]: thread t -> col t>>2, 4 bf16 chunk
  {
    const int col = t >> 2;
    const int seg = t & 3;
    ushort4 vv = *(const ushort4*)&ldsT[col][seg * 4];
    *(ushort4*)&WhT[col * NN + rowblk + seg * 4] = vv;
  }
}

// ---------------------------------------------------------------------------
// Kernel B: per (rowblk, jsplit): mask->exp->p(bf16,LDS)->MFMA PV partials.
// grid 512*JS, 256 thr = 4 waves. Each block: 16 rows x JCHUNK cols.
// Phase 1: thread t covers rows {t>>5, (t>>5)+8}, cols 8*(t&31)..+7.
//          p stored bf16 in LDS, XOR-swizzled (byte ^= (row&7)<<4).
// Phase 2: wave w -> output cols [16w,16w+16); 8 K-frags per tile;
//          A from LDS (swizzled), B from WhT global (L2-hot);
//          mfma_f32_16x16x32_bf16, f32x4 accumulator.
// Partials: num[jsplit][row][64], den[jsplit][row] — block-owned, no atomics.
// ---------------------------------------------------------------------------
__global__ __launch_bounds__(256) void gat_attn2(
    const int* __restrict__ adj, const unsigned short* __restrict__ WhT,
    const float* __restrict__ Wh1, const float* __restrict__ Wh2,
    float* __restrict__ num, float* __restrict__ den) {
  __shared__ __align__(16) unsigned short p_lds[TI * TJ];  // 8 KB
  __shared__ float den_lds[TI];

  const int t = threadIdx.x;
  const int jsplit = blockIdx.x & (JS - 1);
  const int i0 = (blockIdx.x >> 2) * TI;   // JS == 4
  const int j0 = jsplit * JCHUNK;

  // phase-1 identity
  const int r0 = t >> 5;           // 0..7 (rows r0, r0+8)
  const int col8 = (t & 31) * 8;   // 0..248
  const float w1_0 = Wh1[i0 + r0];
  const float w1_1 = Wh1[i0 + r0 + 8];

  // phase-2 identity
  const int w = t >> 6;
  const int l = t & 63;
  const int arow = l & 15;               // MFMA A row / D col index
  const int kg = l >> 4;                 // k-group 0..3
  const int colw = w * 16 + arow;        // output column this lane owns

  float ds0 = 0.f, ds1 = 0.f;
  f32x4 acc = {0.f, 0.f, 0.f, 0.f};

  const int wr_byte0 = (r0 * TJ + col8) * 2 ^ ((r0 & 7) << 4);
  const int wr_byte1 = ((r0 + 8) * TJ + col8) * 2 ^ ((r0 & 7) << 4);
  const int rd_base = (arow * TJ) * 2 ^ ((arow & 7) << 4);

  for (int jb = j0; jb < j0 + JCHUNK; jb += TJ) {
    // ---- phase 1: p = adj ? exp(lrelu(Wh1_i + Wh2_j)) : 0 -> bf16 LDS ----
    const int4* ap0 = (const int4*)&adj[(i0 + r0) * NN + jb + col8];
    const int4* ap1 = (const int4*)&adj[(i0 + r0 + 8) * NN + jb + col8];
    int4 a00 = ap0[0], a01 = ap0[1];
    int4 a10 = ap1[0], a11 = ap1[1];
    float4 w2a = *(const float4*)&Wh2[jb + col8];
    float4 w2b = *(const float4*)&Wh2[jb + col8 + 4];
    float w2v[8] = {w2a.x, w2a.y, w2a.z, w2a.w, w2b.x, w2b.y, w2b.z, w2b.w};
    int am0[8] = {a00.x, a00.y, a00.z, a00.w, a01.x, a01.y, a01.z, a01.w};
    int am1[8] = {a10.x, a10.y, a10.z, a10.w, a11.x, a11.y, a11.z, a11.w};

    short8v pv0, pv1;
#pragma unroll
    for (int e = 0; e < 8; ++e) {
      float v0 = w1_0 + w2v[e];
      v0 = v0 > 0.f ? v0 : LRELU_ALPHA * v0;
      float p0 = (am0[e] > 0) ? __expf(v0) : 0.f;
      ds0 += p0;
      pv0[e] = (short)f2bf(p0);
      float v1 = w1_1 + w2v[e];
      v1 = v1 > 0.f ? v1 : LRELU_ALPHA * v1;
      float p1 = (am1[e] > 0) ? __expf(v1) : 0.f;
      ds1 += p1;
      pv1[e] = (short)f2bf(p1);
    }
    *(short8v*)((char*)p_lds + wr_byte0) = pv0;
    *(short8v*)((char*)p_lds + wr_byte1) = pv1;
    __syncthreads();

    // ---- phase 2: PV MFMA over this tile ----
    const unsigned short* bptr = &WhT[colw * NN + jb + kg * 8];
#pragma unroll
    for (int kt = 0; kt < 8; ++kt) {
      short8v af = *(const short8v*)((const char*)p_lds +
                                     (rd_base ^ ((kt * 32 + kg * 8) * 2)));
      short8v bf = *(const short8v*)(bptr + kt * 32);
      acc = __builtin_amdgcn_mfma_f32_16x16x32_bf16(af, bf, acc, 0, 0, 0);
    }
    __syncthreads();  // p_lds reused next tile
  }

  // ---- den: half-wave shfl reduce, rows disjoint across waves ----
#pragma unroll
  for (int off = 16; off; off >>= 1) {
    ds0 += __shfl_xor(ds0, off);
    ds1 += __shfl_xor(ds1, off);
  }
  if ((t & 31) == 0) {             // lanes 0 and 32 of each wave
    const int rr = t >> 5;         // == row index 2w or 2w+1
    den_lds[rr] = ds0;
    den_lds[rr + 8] = ds1;
  }
  __syncthreads();
  if (t < TI) den[jsplit * NN + i0 + t] = den_lds[t];

  // ---- num partial: C/D layout col=l&15, row=(l>>4)*4+reg ----
#pragma unroll
  for (int r = 0; r < 4; ++r) {
    num[(jsplit * NN + i0 + kg * 4 + r) * FOUT + colw] = acc[r];
  }
}

// ---------------------------------------------------------------------------
// Kernel C: out = elu(sum_s num / sum_s den). grid 2048 x 256.
// ---------------------------------------------------------------------------
__global__ __launch_bounds__(256) void gat_comb(
    const float* __restrict__ num, const float* __restrict__ den,
    float* __restrict__ out) {
  const int idx = blockIdx.x * 256 + threadIdx.x;
  const int row = idx >> 6;
  float n = 0.f, d = 0.f;
#pragma unroll
  for (int s = 0; s < JS; ++s) {
    n += num[s * NN * FOUT + idx];
    d += den[s * NN + row];
  }
  float v = n / d;
  out[idx] = v > 0.f ? v : expm1f(v);
}

extern "C" void kernel_launch(void* const* d_in, const int* in_sizes, int n_in,
                              void* d_out, int out_size, void* d_ws,
                              size_t ws_size, hipStream_t stream) {
  const float* h = (const float*)d_in[0];
  const int* adj = (const int*)d_in[1];
  const float* W = (const float*)d_in[2];
  const float* a = (const float*)d_in[3];
  float* out = (float*)d_out;

  unsigned short* WhT = (unsigned short*)d_ws;          // 1 MB bf16 [64][8192]
  float* Wh1 = (float*)((char*)d_ws + (1 << 20));       // 32 KB
  float* Wh2 = Wh1 + NN;                                // 32 KB
  float* num = Wh2 + NN;                                // JS*2MB = 8 MB
  float* den = num + JS * NN * FOUT;                    // 128 KB

  gat_wh2<<<NN / TI, 256, 0, stream>>>(h, W, a, WhT, Wh1, Wh2);
  gat_attn2<<<(NN / TI) * JS, 256, 0, stream>>>(adj, WhT, Wh1, Wh2, num, den);
  gat_comb<<<NN * FOUT / 256, 256, 0, stream>>>(num, den, out);
}

// Round 5
// 100.864 us; speedup vs baseline: 5.0665x; 1.1593x over previous
//
#include <hip/hip_runtime.h>
#include <hip/hip_bf16.h>
#include <math.h>

#define NN 8192
#define FIN 256
#define FOUT 64
#define LRELU_ALPHA 0.2f
#define TI 16          // rows per block (MFMA M)
#define TJ 256         // j-tile width
#define JS 4           // j-range split factor (occupancy)
#define JCHUNK (NN / JS)

typedef __attribute__((ext_vector_type(8))) short short8v;
typedef __attribute__((ext_vector_type(4))) float f32x4;

static __device__ inline unsigned short f2bf(float f) {
  __hip_bfloat16 b = __float2bfloat16(f);   // HW cvt (m240: scalar cast is fast)
  return *reinterpret_cast<unsigned short*>(&b);
}

// ---------------------------------------------------------------------------
// WhF fragment layout (bf16): for Wh[k][col],
//   flat = ((k>>5)*4 + (col>>4))*512 + (((k>>3)&3)*16 + (col&15))*8 + (k&7)
// so that in kernel B, wave w / lane l reads its 16x32 B-fragment for k-tile
// kblk as ONE coalesced 16B/lane load: &WhF[(kblk*4 + w)*512 + l*8].
// (B-frag: lane l holds B[k=kg*8+e][n=l&15], kg=l>>4 — m89-verified family.)
// ---------------------------------------------------------------------------

// ---------------------------------------------------------------------------
// Kernel A: Wh = h @ W (f32 math); writes WhF (bf16 fragment order),
// Wh1 = Wh@a1, Wh2 = Wh@a2 (f32). grid 512 x 256 thr.
// Wave w owns rows blk*16 + w*4 .. +3; lane c = column. Thread's 4 accs are
// 4 consecutive k at fixed col -> one contiguous ushort4 in WhF (e=k&7 run).
// ---------------------------------------------------------------------------
__global__ __launch_bounds__(256) void gat_wh3(
    const float* __restrict__ h, const float* __restrict__ W,
    const float* __restrict__ a, unsigned short* __restrict__ WhF,
    float* __restrict__ Wh1, float* __restrict__ Wh2) {
  const int t = threadIdx.x;
  const int w = t >> 6;
  const int c = t & 63;
  const int row0 = blockIdx.x * TI + w * 4;

  float acc0 = 0.f, acc1 = 0.f, acc2 = 0.f, acc3 = 0.f;
  for (int k = 0; k < FIN; k += 4) {
    const float4 h0 = *(const float4*)&h[(row0 + 0) * FIN + k];  // uniform
    const float4 h1 = *(const float4*)&h[(row0 + 1) * FIN + k];
    const float4 h2 = *(const float4*)&h[(row0 + 2) * FIN + k];
    const float4 h3 = *(const float4*)&h[(row0 + 3) * FIN + k];
    const float* h0p = (const float*)&h0;
    const float* h1p = (const float*)&h1;
    const float* h2p = (const float*)&h2;
    const float* h3p = (const float*)&h3;
#pragma unroll
    for (int kk = 0; kk < 4; ++kk) {
      const float wv = W[(k + kk) * FOUT + c];  // coalesced 256B, L2-hot
      acc0 = fmaf(h0p[kk], wv, acc0);
      acc1 = fmaf(h1p[kk], wv, acc1);
      acc2 = fmaf(h2p[kk], wv, acc2);
      acc3 = fmaf(h3p[kk], wv, acc3);
    }
  }

  const float a1 = a[c];
  const float a2 = a[FOUT + c];
  float accs[4] = {acc0, acc1, acc2, acc3};
#pragma unroll
  for (int rr = 0; rr < 4; ++rr) {
    float v1 = accs[rr] * a1;
    float v2 = accs[rr] * a2;
#pragma unroll
    for (int off = 32; off; off >>= 1) {
      v1 += __shfl_xor(v1, off);
      v2 += __shfl_xor(v2, off);
    }
    if (c == 0) {
      Wh1[row0 + rr] = v1;
      Wh2[row0 + rr] = v2;
    }
  }

  // WhF store: 4 consecutive e at (k=row0, col=c) -> one 8B ushort4
  const int basef = ((row0 >> 5) * 4 + (c >> 4)) * 512 +
                    (((row0 >> 3) & 3) * 16 + (c & 15)) * 8 + (row0 & 7);
  ushort4 st;
  st.x = f2bf(acc0);
  st.y = f2bf(acc1);
  st.z = f2bf(acc2);
  st.w = f2bf(acc3);
  *(ushort4*)&WhF[basef] = st;
}

// ---------------------------------------------------------------------------
// Kernel B: per (rowblk, jsplit): mask->exp->p(bf16,LDS dbuf)->MFMA partials.
// grid 2048, 256 thr = 4 waves; ONE barrier per tile (p_lds double-buffered);
// adj/Wh2 for tile t+1 issued right after tile t's exp compute (issue-early),
// in flight across barrier + MFMA phase.
// Phase 1: thread t covers rows {t>>5, (t>>5)+8}, cols 8*(t&31)..+7;
//          p bf16 in LDS, XOR-swizzled (byte ^= (row&7)<<4) -> balanced banks.
// Phase 2: wave w -> output cols [16w,16w+16); A from LDS (swizzled),
//          B from WhF (1KB coalesced wave-loads, L2-hot); 16x16x32 bf16 MFMA.
// Partials: num[jsplit][row][64], den[jsplit][row] — block-owned, no atomics.
// ---------------------------------------------------------------------------
__global__ __launch_bounds__(256) void gat_attn3(
    const int* __restrict__ adj, const unsigned short* __restrict__ WhF,
    const float* __restrict__ Wh1, const float* __restrict__ Wh2,
    float* __restrict__ num, float* __restrict__ den) {
  __shared__ __align__(16) unsigned short p_lds[2][TI * TJ];  // 2 x 8 KB
  __shared__ float den_lds[TI];

  const int t = threadIdx.x;
  const int jsplit = blockIdx.x & (JS - 1);
  const int i0 = (blockIdx.x >> 2) * TI;   // JS == 4
  const int j0 = jsplit * JCHUNK;

  // phase-1 identity
  const int r0 = t >> 5;           // rows r0, r0+8
  const int col8 = (t & 31) * 8;
  const float w1_0 = Wh1[i0 + r0];
  const float w1_1 = Wh1[i0 + r0 + 8];

  // phase-2 identity
  const int w = t >> 6;
  const int l = t & 63;
  const int arow = l & 15;
  const int kg = l >> 4;
  const int colw = w * 16 + arow;

  float ds0 = 0.f, ds1 = 0.f;
  f32x4 acc = {0.f, 0.f, 0.f, 0.f};

  const int wr0 = ((r0 * TJ + col8) * 2) ^ ((r0 & 7) << 4);
  const int wr1 = (((r0 + 8) * TJ + col8) * 2) ^ ((r0 & 7) << 4);
  const int rdb = (arow * TJ * 2) ^ ((arow & 7) << 4);

  // ---- prologue: load tile 0 ----
  int4 a00, a01, a10, a11;
  float4 w2a, w2b;
  {
    const int4* ap0 = (const int4*)&adj[(size_t)(i0 + r0) * NN + j0 + col8];
    const int4* ap1 = (const int4*)&adj[(size_t)(i0 + r0 + 8) * NN + j0 + col8];
    a00 = ap0[0]; a01 = ap0[1];
    a10 = ap1[0]; a11 = ap1[1];
    w2a = *(const float4*)&Wh2[j0 + col8];
    w2b = *(const float4*)&Wh2[j0 + col8 + 4];
  }

  for (int jb = j0, it = 0; jb < j0 + JCHUNK; jb += TJ, ++it) {
    unsigned short* pl = &p_lds[it & 1][0];

    // ---- phase 1: p = adj ? exp(lrelu(Wh1_i + Wh2_j)) : 0 -> bf16 LDS ----
    const float w2v[8] = {w2a.x, w2a.y, w2a.z, w2a.w,
                          w2b.x, w2b.y, w2b.z, w2b.w};
    const int am0[8] = {a00.x, a00.y, a00.z, a00.w, a01.x, a01.y, a01.z, a01.w};
    const int am1[8] = {a10.x, a10.y, a10.z, a10.w, a11.x, a11.y, a11.z, a11.w};

    short8v pv0, pv1;
#pragma unroll
    for (int e = 0; e < 8; ++e) {
      float v0 = w1_0 + w2v[e];
      v0 = v0 > 0.f ? v0 : LRELU_ALPHA * v0;
      float p0 = (am0[e] > 0) ? __expf(v0) : 0.f;
      ds0 += p0;
      pv0[e] = (short)f2bf(p0);
      float v1 = w1_1 + w2v[e];
      v1 = v1 > 0.f ? v1 : LRELU_ALPHA * v1;
      float p1 = (am1[e] > 0) ? __expf(v1) : 0.f;
      ds1 += p1;
      pv1[e] = (short)f2bf(p1);
    }
    *(short8v*)((char*)pl + wr0) = pv0;
    *(short8v*)((char*)pl + wr1) = pv1;

    // ---- issue next tile's loads (in flight across barrier + MFMA) ----
    if (jb + TJ < j0 + JCHUNK) {
      const int jn = jb + TJ;
      const int4* ap0 = (const int4*)&adj[(size_t)(i0 + r0) * NN + jn + col8];
      const int4* ap1 =
          (const int4*)&adj[(size_t)(i0 + r0 + 8) * NN + jn + col8];
      a00 = ap0[0]; a01 = ap0[1];
      a10 = ap1[0]; a11 = ap1[1];
      w2a = *(const float4*)&Wh2[jn + col8];
      w2b = *(const float4*)&Wh2[jn + col8 + 4];
    }
    __syncthreads();

    // ---- phase 2: PV MFMA over this tile ----
    const int kblk0 = jb >> 5;
#pragma unroll
    for (int kt = 0; kt < 8; ++kt) {
      short8v af = *(const short8v*)((const char*)pl +
                                     (rdb ^ ((kt * 32 + kg * 8) * 2)));
      short8v bf = *(const short8v*)&WhF[((kblk0 + kt) * 4 + w) * 512 + l * 8];
      acc = __builtin_amdgcn_mfma_f32_16x16x32_bf16(af, bf, acc, 0, 0, 0);
    }
    // no second barrier: next iteration writes the other p_lds buffer
  }

  // ---- den: half-wave shfl reduce, rows disjoint across waves ----
#pragma unroll
  for (int off = 16; off; off >>= 1) {
    ds0 += __shfl_xor(ds0, off);
    ds1 += __shfl_xor(ds1, off);
  }
  if ((t & 31) == 0) {
    const int rr = t >> 5;
    den_lds[rr] = ds0;
    den_lds[rr + 8] = ds1;
  }
  __syncthreads();
  if (t < TI) den[jsplit * NN + i0 + t] = den_lds[t];

  // ---- num partial: C/D layout col=l&15, row=(l>>4)*4+reg ----
#pragma unroll
  for (int r = 0; r < 4; ++r) {
    num[(size_t)(jsplit * NN + i0 + kg * 4 + r) * FOUT + colw] = acc[r];
  }
}

// ---------------------------------------------------------------------------
// Kernel C: out = elu(sum_s num / sum_s den). grid 2048 x 256.
// ---------------------------------------------------------------------------
__global__ __launch_bounds__(256) void gat_comb(
    const float* __restrict__ num, const float* __restrict__ den,
    float* __restrict__ out) {
  const int idx = blockIdx.x * 256 + threadIdx.x;
  const int row = idx >> 6;
  float n = 0.f, d = 0.f;
#pragma unroll
  for (int s = 0; s < JS; ++s) {
    n += num[(size_t)s * NN * FOUT + idx];
    d += den[s * NN + row];
  }
  float v = n / d;
  out[idx] = v > 0.f ? v : expm1f(v);
}

extern "C" void kernel_launch(void* const* d_in, const int* in_sizes, int n_in,
                              void* d_out, int out_size, void* d_ws,
                              size_t ws_size, hipStream_t stream) {
  const float* h = (const float*)d_in[0];
  const int* adj = (const int*)d_in[1];
  const float* W = (const float*)d_in[2];
  const float* a = (const float*)d_in[3];
  float* out = (float*)d_out;

  unsigned short* WhF = (unsigned short*)d_ws;          // 1 MB bf16 fragments
  float* Wh1 = (float*)((char*)d_ws + (1 << 20));       // 32 KB
  float* Wh2 = Wh1 + NN;                                // 32 KB
  float* num = Wh2 + NN;                                // 8 MB
  float* den = num + (size_t)JS * NN * FOUT;            // 128 KB

  gat_wh3<<<NN / TI, 256, 0, stream>>>(h, W, a, WhF, Wh1, Wh2);
  gat_attn3<<<(NN / TI) * JS, 256, 0, stream>>>(adj, WhF, Wh1, Wh2, num, den);
  gat_comb<<<NN * FOUT / 256, 256, 0, stream>>>(num, den, out);
}